// Round 7
// baseline (450.844 us; speedup 1.0000x reference)
//
#include <hip/hip_runtime.h>

// Morph2D — DIAGNOSTIC BUILD R7: R6 structure (4 rows x 4 cols / thread)
// wrapped in a 4x runtime-opaque repeat (img + it*zero, zero==0) with exact
// recombination ((r+r+r+r)*0.25f). Solves dur(4x)=S+4V against kernel(1x)=S+V
// to split per-body VALU time V from one-time memory/stall S.

#define HH 512
#define WW 512

#define RFL(x) __int_as_float(__builtin_amdgcn_readfirstlane(__float_as_int(x)))
#define CSWAP(a,b) { float lo_ = fminf(v[a], v[b]); float hi_ = fmaxf(v[a], v[b]); v[a] = lo_; v[b] = hi_; }
#define SORT9 \
    CSWAP(0,3) CSWAP(1,7) CSWAP(2,5) CSWAP(4,8) \
    CSWAP(0,7) CSWAP(2,4) CSWAP(3,8) CSWAP(5,6) \
    CSWAP(0,2) CSWAP(1,3) CSWAP(4,5) CSWAP(7,8) \
    CSWAP(1,4) CSWAP(3,6) CSWAP(5,7) \
    CSWAP(0,1) CSWAP(2,4) CSWAP(3,5) CSWAP(6,8) \
    CSWAP(2,3) CSWAP(4,5) CSWAP(6,7) \
    CSWAP(1,2) CSWAP(3,4) CSWAP(5,6)

__global__ __launch_bounds__(256, 4) void morph2d_kernel(
    const float* __restrict__ x, const float* __restrict__ se9,
    const float* __restrict__ rank, float* __restrict__ out,
    int zero, float invR)
{
    int nper = gridDim.x >> 3;
    int lb   = (blockIdx.x & 7) * nper + (blockIdx.x >> 3);
    int g    = lb * 256 + threadIdx.x;       // 524,288 total, exact

    int gx = g & 127;             // x-group of 4 px
    int rg = (g >> 7) & 127;      // row-group of 4 rows (wave-uniform)
    int b  = g >> 14;             // batch
    int x4 = gx << 2;
    int y0 = rg << 2;

    const float* img0 = x + (size_t)b * (HH * WW);
    int offL = max(x4 - 1, 0);
    int offR = min(x4 + 4, WW - 1);
    bool xl = (x4 == 0);
    bool xr = (x4 + 4 >= WW);

    // softmax(rank) (1/s deferred to invR fold) + se, scalarized
    float w0,w1,w2,w3,w4,w5,w6,w7,w8;
    float s0,s1,s2,s3,s4,s5,s6,s7,s8;
    {
        float e[9]; float s = 0.f;
        #pragma unroll
        for (int i = 0; i < 9; ++i) { e[i] = __expf(rank[i]); s += e[i]; }
        float inv = 1.0f / s;
        w0=RFL(e[0]*inv); w1=RFL(e[1]*inv); w2=RFL(e[2]*inv);
        w3=RFL(e[3]*inv); w4=RFL(e[4]*inv); w5=RFL(e[5]*inv);
        w6=RFL(e[6]*inv); w7=RFL(e[7]*inv); w8=RFL(e[8]*inv);
        s0=RFL(se9[0]); s1=RFL(se9[1]); s2=RFL(se9[2]); s3=RFL(se9[3]);
        s4=RFL(se9[4]); s5=RFL(se9[5]); s6=RFL(se9[6]); s7=RFL(se9[7]); s8=RFL(se9[8]);
    }

    float acc[4][4];
    #pragma unroll
    for (int r = 0; r < 4; ++r)
        #pragma unroll
        for (int j = 0; j < 4; ++j) acc[r][j] = 0.f;

    #pragma unroll
    for (int it = 0; it < 4; ++it) {
        const float* img = img0 + (size_t)it * zero;   // == img0 at runtime

        float R[6][6];   // rows y0-1 .. y0+4, cols x4-1 .. x4+4
        #pragma unroll
        for (int r = 1; r <= 4; ++r) {
            const float* p = img + (y0 - 1 + r) * WW;
            float4 c = *(const float4*)(p + x4);
            R[r][0] = p[offL]; R[r][1] = c.x; R[r][2] = c.y;
            R[r][3] = c.z;     R[r][4] = c.w; R[r][5] = p[offR];
        }
        {
            int ry = y0 - 1;
            const float* p = img + max(ry, 0) * WW;
            float4 c = *(const float4*)(p + x4);
            float  m = (ry >= 0) ? 1.f : 0.f;
            R[0][0] = p[offL] * m; R[0][1] = c.x * m; R[0][2] = c.y * m;
            R[0][3] = c.z * m;     R[0][4] = c.w * m; R[0][5] = p[offR] * m;
        }
        {
            int ry = y0 + 4;
            const float* p = img + min(ry, HH - 1) * WW;
            float4 c = *(const float4*)(p + x4);
            float  m = (ry < HH) ? 1.f : 0.f;
            R[5][0] = p[offL] * m; R[5][1] = c.x * m; R[5][2] = c.y * m;
            R[5][3] = c.z * m;     R[5][4] = c.w * m; R[5][5] = p[offR] * m;
        }

        #pragma unroll
        for (int r = 0; r < 6; ++r) {
            R[r][0] = xl ? 0.f : R[r][0];
            R[r][5] = xr ? 0.f : R[r][5];
        }

        #pragma unroll
        for (int r = 0; r < 4; ++r) {
            #pragma unroll
            for (int j = 0; j < 4; ++j) {
                float v[9];
                v[0] = R[r  ][j]*s0; v[1] = R[r  ][j+1]*s1; v[2] = R[r  ][j+2]*s2;
                v[3] = R[r+1][j]*s3; v[4] = R[r+1][j+1]*s4; v[5] = R[r+1][j+2]*s5;
                v[6] = R[r+2][j]*s6; v[7] = R[r+2][j+1]*s7; v[8] = R[r+2][j+2]*s8;
                SORT9
                float d0 = fmaf(v[0], w0, v[1]*w1);
                float d1 = fmaf(v[2], w2, v[3]*w3);
                float d2 = fmaf(v[4], w4, v[5]*w5);
                float d3 = fmaf(v[6], w6, v[7]*w7);
                float d4 = v[8]*w8;
                acc[r][j] += (d0 + d1) + (d2 + d3) + d4;
            }
        }
    }

    #pragma unroll
    for (int r = 0; r < 4; ++r) {
        float4 o = { acc[r][0]*invR, acc[r][1]*invR, acc[r][2]*invR, acc[r][3]*invR };
        *(float4*)(out + (((size_t)b * HH + (y0 + r)) * WW + x4)) = o;
    }
}

extern "C" void kernel_launch(void* const* d_in, const int* in_sizes, int n_in,
                              void* d_out, int out_size, void* d_ws, size_t ws_size,
                              hipStream_t stream) {
    const float* x    = (const float*)d_in[0];
    const float* se   = (const float*)d_in[1];
    const float* rank = (const float*)d_in[2];
    float* out = (float*)d_out;

    const int total_threads = 32 * (HH / 4) * (WW / 4);   // 524,288
    morph2d_kernel<<<total_threads / 256, 256, 0, stream>>>(
        x, se, rank, out, /*zero=*/0, /*invR=*/0.25f);
}

// Round 8
// 90.269 us; speedup vs baseline: 4.9944x; 4.9944x over previous
//
#include <hip/hip_runtime.h>

// Morph2D soft rank-order filter:
//   patches(3x3, zero-pad SAME) * se -> sort ascending -> dot softmax(rank)
// x: [32,512,512,1] fp32 -> out same shape.
//
// R8: 4x4 px/thread, plain __launch_bounds__(256) — R7 proved (256,4)
// forces VGPR=64 + massive scratch spill (840MB writes). Sort uses
// v_min3/med3/max3 ternary comparators: 29 ops vs 25-CE/50-op binary net.

#define HH 512
#define WW 512

#define RFL(x) __int_as_float(__builtin_amdgcn_readfirstlane(__float_as_int(x)))
#define MIN3(a,b,c) fminf(fminf(a,b),c)
#define MAX3(a,b,c) fmaxf(fmaxf(a,b),c)
#define MED3(a,b,c) __builtin_amdgcn_fmed3f(a,b,c)
// full 3-sort: a<=b<=c afterwards (3 inst: v_min3/v_med3/v_max3)
#define TSORT(a,b,c) { float t0_=MIN3(a,b,c), t1_=MED3(a,b,c), t2_=MAX3(a,b,c); a=t0_; b=t1_; c=t2_; }

__global__ __launch_bounds__(256) void morph2d_kernel(
    const float* __restrict__ x, const float* __restrict__ se9,
    const float* __restrict__ rank, float* __restrict__ out)
{
    // XCD-aware swizzle: contiguous chunk of blocks per XCD
    int nper = gridDim.x >> 3;
    int lb   = (blockIdx.x & 7) * nper + (blockIdx.x >> 3);
    int g    = lb * 256 + threadIdx.x;       // 524,288 total, exact

    int gx = g & 127;             // x-group of 4 px
    int rg = (g >> 7) & 127;      // row-group of 4 rows (wave-uniform)
    int b  = g >> 14;             // batch
    int x4 = gx << 2;
    int y0 = rg << 2;

    const float* img = x + (size_t)b * (HH * WW);
    int offL = max(x4 - 1, 0);
    int offR = min(x4 + 4, WW - 1);

    float R[6][6];   // rows y0-1 .. y0+4, cols x4-1 .. x4+4

    // ---- interior rows (always in-bounds): loads back-to-back ----
    #pragma unroll
    for (int r = 1; r <= 4; ++r) {
        const float* p = img + (y0 - 1 + r) * WW;
        float4 c = *(const float4*)(p + x4);
        R[r][0] = p[offL]; R[r][1] = c.x; R[r][2] = c.y;
        R[r][3] = c.z;     R[r][4] = c.w; R[r][5] = p[offR];
    }
    // ---- top halo row (zero iff y0 == 0) ----
    {
        int ry = y0 - 1;
        const float* p = img + max(ry, 0) * WW;
        float4 c = *(const float4*)(p + x4);
        float  m = (ry >= 0) ? 1.f : 0.f;
        R[0][0] = p[offL] * m; R[0][1] = c.x * m; R[0][2] = c.y * m;
        R[0][3] = c.z * m;     R[0][4] = c.w * m; R[0][5] = p[offR] * m;
    }
    // ---- bottom halo row (zero iff y0 + 4 == HH) ----
    {
        int ry = y0 + 4;
        const float* p = img + min(ry, HH - 1) * WW;
        float4 c = *(const float4*)(p + x4);
        float  m = (ry < HH) ? 1.f : 0.f;
        R[5][0] = p[offL] * m; R[5][1] = c.x * m; R[5][2] = c.y * m;
        R[5][3] = c.z * m;     R[5][4] = c.w * m; R[5][5] = p[offR] * m;
    }

    // ---- softmax(rank) (1/s folded) + se, scalarized, under load shadow ----
    float w0,w1,w2,w3,w4,w5,w6,w7,w8;
    float s0,s1,s2,s3,s4,s5,s6,s7,s8;
    {
        float e[9]; float s = 0.f;
        #pragma unroll
        for (int i = 0; i < 9; ++i) { e[i] = __expf(rank[i]); s += e[i]; }
        float inv = 1.0f / s;
        w0=RFL(e[0]*inv); w1=RFL(e[1]*inv); w2=RFL(e[2]*inv);
        w3=RFL(e[3]*inv); w4=RFL(e[4]*inv); w5=RFL(e[5]*inv);
        w6=RFL(e[6]*inv); w7=RFL(e[7]*inv); w8=RFL(e[8]*inv);
        s0=RFL(se9[0]); s1=RFL(se9[1]); s2=RFL(se9[2]); s3=RFL(se9[3]);
        s4=RFL(se9[4]); s5=RFL(se9[5]); s6=RFL(se9[6]); s7=RFL(se9[7]); s8=RFL(se9[8]);
    }

    // ---- x-edge zeroing (branchless cndmask) ----
    bool xl = (x4 == 0);
    bool xr = (x4 + 4 >= WW);
    #pragma unroll
    for (int r = 0; r < 6; ++r) {
        R[r][0] = xl ? 0.f : R[r][0];
        R[r][5] = xr ? 0.f : R[r][5];
    }

    // ---- 16 px: se-weight, ternary-sort, dot ----
    #pragma unroll
    for (int r = 0; r < 4; ++r) {
        float res[4];
        #pragma unroll
        for (int j = 0; j < 4; ++j) {
            float v0 = R[r  ][j]*s0, v1 = R[r  ][j+1]*s1, v2 = R[r  ][j+2]*s2;
            float v3 = R[r+1][j]*s3, v4 = R[r+1][j+1]*s4, v5 = R[r+1][j+2]*s5;
            float v6 = R[r+2][j]*s6, v7 = R[r+2][j+1]*s7, v8 = R[r+2][j+2]*s8;

            // 9-sort via 3x3 tableau: rows, cols, then 4 CE + 1 TSORT finish
            TSORT(v0, v1, v2)            // rows
            TSORT(v3, v4, v5)
            TSORT(v6, v7, v8)
            TSORT(v0, v3, v6)            // cols (rows remain sorted)
            TSORT(v1, v4, v7)
            TSORT(v2, v5, v8)
            // tableau: v0=min, v8=max; finish the middle 7
            float r1 = fminf(v1, v3), p = fmaxf(v1, v3);
            float r7 = fmaxf(v5, v7), q = fminf(v5, v7);
            TSORT(v2, v4, v6)            // anti-diagonal; v4 = rank4
            float r2 = fminf(p, v2), r3 = fmaxf(p, v2);
            float r5 = fminf(q, v6), r6 = fmaxf(q, v6);

            float acc = v0 * w0;
            acc = fmaf(r1, w1, acc);
            acc = fmaf(r2, w2, acc);
            acc = fmaf(r3, w3, acc);
            acc = fmaf(v4, w4, acc);
            acc = fmaf(r5, w5, acc);
            acc = fmaf(r6, w6, acc);
            acc = fmaf(r7, w7, acc);
            acc = fmaf(v8, w8, acc);
            res[j] = acc;
        }
        float4 o = { res[0], res[1], res[2], res[3] };
        *(float4*)(out + (((size_t)b * HH + (y0 + r)) * WW + x4)) = o;
    }
}

extern "C" void kernel_launch(void* const* d_in, const int* in_sizes, int n_in,
                              void* d_out, int out_size, void* d_ws, size_t ws_size,
                              hipStream_t stream) {
    const float* x    = (const float*)d_in[0];
    const float* se   = (const float*)d_in[1];
    const float* rank = (const float*)d_in[2];
    float* out = (float*)d_out;

    const int total_threads = 32 * (HH / 4) * (WW / 4);   // 524,288
    morph2d_kernel<<<total_threads / 256, 256, 0, stream>>>(x, se, rank, out);
}

// Round 9
// 89.296 us; speedup vs baseline: 5.0489x; 1.0109x over previous
//
#include <hip/hip_runtime.h>

// Morph2D soft rank-order filter:
//   patches(3x3, zero-pad SAME) * se -> sort ascending -> dot softmax(rank)
// x: [32,512,512,1] fp32 -> out same shape.
//
// R9: R8 (4x4 px/thread, ternary min3/med3/max3 sort) + shuffle-based halo:
// only 6 dense float4 loads + 1 two-lane-masked scalar load per row; left/
// right window columns come from neighbor lanes via __shfl_up/__shfl_down.
// Cuts per-wave L1 line-accesses ~2.6x vs per-thread scalar halo gathers.

#define HH 512
#define WW 512

#define RFL(x) __int_as_float(__builtin_amdgcn_readfirstlane(__float_as_int(x)))
#define MIN3(a,b,c) fminf(fminf(a,b),c)
#define MAX3(a,b,c) fmaxf(fmaxf(a,b),c)
#define MED3(a,b,c) __builtin_amdgcn_fmed3f(a,b,c)
#define TSORT(a,b,c) { float t0_=MIN3(a,b,c), t1_=MED3(a,b,c), t2_=MAX3(a,b,c); a=t0_; b=t1_; c=t2_; }

__global__ __launch_bounds__(256) void morph2d_kernel(
    const float* __restrict__ x, const float* __restrict__ se9,
    const float* __restrict__ rank, float* __restrict__ out)
{
    // XCD-aware swizzle: contiguous chunk of blocks per XCD
    int nper = gridDim.x >> 3;
    int lb   = (blockIdx.x & 7) * nper + (blockIdx.x >> 3);
    int g    = lb * 256 + threadIdx.x;       // 524,288 total, exact

    int gx = g & 127;             // x-group of 4 px
    int rg = (g >> 7) & 127;      // row-group of 4 rows (wave-uniform)
    int b  = g >> 14;             // batch
    int x4 = gx << 2;
    int y0 = rg << 2;
    int lane = threadIdx.x & 63;

    const float* img = x + (size_t)b * (HH * WW);

    // wave-edge halo lanes: lane 0 loads col x4-1, lane 63 loads col x4+4
    bool eL = (lane == 0)  && (x4 > 0);
    bool eR = (lane == 63) && (x4 + 4 < WW);
    bool eAny = eL || eR;
    int  eoff = eL ? (x4 - 1) : (x4 + 4);

    // ---- issue all global loads (6 float4 + 6 masked scalars) ----
    float4 c[6];
    float  eg[6];
    float  mm[6];
    #pragma unroll
    for (int r = 0; r < 6; ++r) {
        int ry  = y0 - 1 + r;
        int ryc = min(max(ry, 0), HH - 1);
        const float* p = img + ryc * WW;
        c[r]  = *(const float4*)(p + x4);
        eg[r] = eAny ? p[eoff] : 0.f;
        mm[r] = (ry >= 0 && ry < HH) ? 1.f : 0.f;   // only rows 0 and 5 can mask
    }

    // ---- softmax(rank) (1/s folded) + se, scalarized, under load shadow ----
    float w0,w1,w2,w3,w4,w5,w6,w7,w8;
    float s0,s1,s2,s3,s4,s5,s6,s7,s8;
    {
        float e[9]; float s = 0.f;
        #pragma unroll
        for (int i = 0; i < 9; ++i) { e[i] = __expf(rank[i]); s += e[i]; }
        float inv = 1.0f / s;
        w0=RFL(e[0]*inv); w1=RFL(e[1]*inv); w2=RFL(e[2]*inv);
        w3=RFL(e[3]*inv); w4=RFL(e[4]*inv); w5=RFL(e[5]*inv);
        w6=RFL(e[6]*inv); w7=RFL(e[7]*inv); w8=RFL(e[8]*inv);
        s0=RFL(se9[0]); s1=RFL(se9[1]); s2=RFL(se9[2]); s3=RFL(se9[3]);
        s4=RFL(se9[4]); s5=RFL(se9[5]); s6=RFL(se9[6]); s7=RFL(se9[7]); s8=RFL(se9[8]);
    }

    // ---- reconstruct 6-col rows: halos from neighbor lanes ----
    float R[6][6];
    #pragma unroll
    for (int r = 0; r < 6; ++r) {
        float lw = __shfl_up(c[r].w, 1);     // lane i-1's c.w  (col x4-1)
        float rx = __shfl_down(c[r].x, 1);   // lane i+1's c.x  (col x4+4)
        float lf = (lane == 0)  ? eg[r] : lw;   // x4==0 -> eg==0 (zero-pad)
        float rt = (lane == 63) ? eg[r] : rx;   // x4+4==WW -> eg==0
        float m  = mm[r];
        R[r][0] = lf * m;     R[r][1] = c[r].x * m; R[r][2] = c[r].y * m;
        R[r][3] = c[r].z * m; R[r][4] = c[r].w * m; R[r][5] = rt * m;
    }

    // ---- 16 px: se-weight, ternary tableau sort (29 ops), dot ----
    #pragma unroll
    for (int r = 0; r < 4; ++r) {
        float res[4];
        #pragma unroll
        for (int j = 0; j < 4; ++j) {
            float v0 = R[r  ][j]*s0, v1 = R[r  ][j+1]*s1, v2 = R[r  ][j+2]*s2;
            float v3 = R[r+1][j]*s3, v4 = R[r+1][j+1]*s4, v5 = R[r+1][j+2]*s5;
            float v6 = R[r+2][j]*s6, v7 = R[r+2][j+1]*s7, v8 = R[r+2][j+2]*s8;

            TSORT(v0, v1, v2)            // rows
            TSORT(v3, v4, v5)
            TSORT(v6, v7, v8)
            TSORT(v0, v3, v6)            // cols (rows remain sorted)
            TSORT(v1, v4, v7)
            TSORT(v2, v5, v8)
            float r1 = fminf(v1, v3), p = fmaxf(v1, v3);
            float r7 = fmaxf(v5, v7), q = fminf(v5, v7);
            TSORT(v2, v4, v6)            // anti-diagonal; v4 = rank 4
            float r2 = fminf(p, v2), r3 = fmaxf(p, v2);
            float r5 = fminf(q, v6), r6 = fmaxf(q, v6);

            float acc = v0 * w0;
            acc = fmaf(r1, w1, acc);
            acc = fmaf(r2, w2, acc);
            acc = fmaf(r3, w3, acc);
            acc = fmaf(v4, w4, acc);
            acc = fmaf(r5, w5, acc);
            acc = fmaf(r6, w6, acc);
            acc = fmaf(r7, w7, acc);
            acc = fmaf(v8, w8, acc);
            res[j] = acc;
        }
        float4 o = { res[0], res[1], res[2], res[3] };
        *(float4*)(out + (((size_t)b * HH + (y0 + r)) * WW + x4)) = o;
    }
}

extern "C" void kernel_launch(void* const* d_in, const int* in_sizes, int n_in,
                              void* d_out, int out_size, void* d_ws, size_t ws_size,
                              hipStream_t stream) {
    const float* x    = (const float*)d_in[0];
    const float* se   = (const float*)d_in[1];
    const float* rank = (const float*)d_in[2];
    float* out = (float*)d_out;

    const int total_threads = 32 * (HH / 4) * (WW / 4);   // 524,288
    morph2d_kernel<<<total_threads / 256, 256, 0, stream>>>(x, se, rank, out);
}